// Round 1
// baseline (242.111 us; speedup 1.0000x reference)
//
#include <hip/hip_runtime.h>
#include <math.h>

#define SD 9216   // S = H*W
#define HH 96     // H = W
#define CC 256    // C
#define NO 768    // 3*C
#define NH 8      // heads
#define DH 32     // head dim

// ---------------- GEMM 1: qkv[s][o] = sum_c x[c][s] * w_qkv[o][c] + b_qkv[o]
// x is [C][S] (channel-first), so A[m=s][k=c] = x[c*S + s]
__global__ __launch_bounds__(256) void qkv_gemm(const float* __restrict__ x,
                                                const float* __restrict__ w,
                                                const float* __restrict__ b,
                                                float* __restrict__ qkv) {
  __shared__ __align__(16) float As[16][68];  // As[kc][m], padded
  __shared__ __align__(16) float Bs[16][68];  // Bs[kc][n], padded
  const int m0 = blockIdx.x * 64;
  const int n0 = blockIdx.y * 64;
  const int tid = threadIdx.x;
  const int tn = tid & 15;   // n-lane (coalesced writes along o)
  const int tm = tid >> 4;   // m-group
  float acc[4][4] = {};      // [i=m][j=n]

  for (int k0 = 0; k0 < CC; k0 += 16) {
    {
      // A tile: 64 m x 16 kc ; float4 along m (coalesced: s contiguous in x)
      const int m4 = (tid & 15) * 4, kc = tid >> 4;
      const float4 v = *(const float4*)(x + (size_t)(k0 + kc) * SD + m0 + m4);
      As[kc][m4 + 0] = v.x; As[kc][m4 + 1] = v.y;
      As[kc][m4 + 2] = v.z; As[kc][m4 + 3] = v.w;
    }
    {
      // B tile: 16 kc x 64 n ; float4 along k (c contiguous in w)
      const int kc4 = (tid & 3) * 4, n = tid >> 2;
      const float4 v = *(const float4*)(w + (size_t)(n0 + n) * CC + k0 + kc4);
      Bs[kc4 + 0][n] = v.x; Bs[kc4 + 1][n] = v.y;
      Bs[kc4 + 2][n] = v.z; Bs[kc4 + 3][n] = v.w;
    }
    __syncthreads();
#pragma unroll
    for (int kc = 0; kc < 16; ++kc) {
      float a[4], bb[4];
#pragma unroll
      for (int i = 0; i < 4; ++i) a[i] = As[kc][tm + 16 * i];
#pragma unroll
      for (int j = 0; j < 4; ++j) bb[j] = Bs[kc][tn + 16 * j];
#pragma unroll
      for (int i = 0; i < 4; ++i)
#pragma unroll
        for (int j = 0; j < 4; ++j) acc[i][j] += a[i] * bb[j];
    }
    __syncthreads();
  }
#pragma unroll
  for (int i = 0; i < 4; ++i) {
    const int s = m0 + tm + 16 * i;
#pragma unroll
    for (int j = 0; j < 4; ++j) {
      const int o = n0 + tn + 16 * j;
      qkv[(size_t)s * NO + o] = acc[i][j] + b[o];
    }
  }
}

// ---------------- Kernel 2: neighborhood attention, one wave per (s, head)
__global__ __launch_bounds__(256) void nattn(const float* __restrict__ qkv,
                                             float* __restrict__ att) {
  const int gw   = (blockIdx.x * 256 + threadIdx.x) >> 6;  // global wave id
  const int lane = threadIdx.x & 63;
  const int wv   = threadIdx.x >> 6;
  const int h = gw & 7;
  const int s = gw >> 3;

  __shared__ __align__(16) float qsh[4][32];

  const int i = s / HH, j = s - i * HH;
  const int ri = min(max(i, 3), HH - 4) - 3;  // clamped window start row
  const int cj = min(max(j, 3), HH - 4) - 3;  // clamped window start col

  const float* qp = qkv + (size_t)s * NO + h * DH;
  if (lane < 32) qsh[wv][lane] = qp[lane];
  __syncthreads();

  // lane -> neighbor (lane < 49)
  const int nr = ri + lane / 7;
  const int nc = cj + lane % 7;
  const int nidx = nr * HH + nc;

  float score = -1e30f;
  if (lane < 49) {
    const float4* kp = (const float4*)(qkv + (size_t)nidx * NO + CC + h * DH);
    const float4* qv = (const float4*)qsh[wv];
    float acc = 0.f;
#pragma unroll
    for (int d4 = 0; d4 < 8; ++d4) {
      const float4 kk = kp[d4], qq = qv[d4];
      acc += kk.x * qq.x; acc += kk.y * qq.y;
      acc += kk.z * qq.z; acc += kk.w * qq.w;
    }
    score = acc * 0.17677669529663687f;  // 32^-0.5
  }

  // wave softmax over 49 (lanes >= 49 contribute -inf / 0)
  float mx = score;
#pragma unroll
  for (int off = 32; off; off >>= 1) mx = fmaxf(mx, __shfl_xor(mx, off));
  float p = (lane < 49) ? __expf(score - mx) : 0.f;
  float sum = p;
#pragma unroll
  for (int off = 32; off; off >>= 1) sum += __shfl_xor(sum, off);
  p /= sum;

  // PV: lanes 0-31 handle even neighbors, 32-63 odd; combine at end
  const int d  = lane & 31;
  const int hi = lane >> 5;
  const float* vbase = qkv + 2 * CC + h * DH + d;
  float o = 0.f;
#pragma unroll
  for (int t = 0; t < 24; ++t) {
    const int jj = 2 * t + hi;
    const float pj = __shfl(p, jj);
    const int nj = __shfl(nidx, jj);
    o += pj * vbase[(size_t)nj * NO];
  }
  {  // neighbor 48 (lo half only)
    const float pj = __shfl(p, 48);
    const int nj = __shfl(nidx, 48);
    if (!hi) o += pj * vbase[(size_t)nj * NO];
  }
  o += __shfl_xor(o, 32);
  if (lane < 32) att[(size_t)s * CC + h * DH + d] = o;
}

// ---------------- GEMM 3: out[o][s] = sum_c att[s][c] * w_out[o][c] + b_out[o]
__global__ __launch_bounds__(256) void out_gemm(const float* __restrict__ att,
                                                const float* __restrict__ w,
                                                const float* __restrict__ b,
                                                float* __restrict__ out) {
  __shared__ __align__(16) float As[16][68];
  __shared__ __align__(16) float Bs[16][68];
  const int m0 = blockIdx.x * 64;
  const int n0 = blockIdx.y * 64;
  const int tid = threadIdx.x;
  const int tm = tid & 15;   // m-lane (coalesced writes along s)
  const int tn = tid >> 4;   // n-group
  float acc[4][4] = {};

  for (int k0 = 0; k0 < CC; k0 += 16) {
    {
      // A tile: att row-major, float4 along k
      const int kc4 = (tid & 3) * 4, m = tid >> 2;
      const float4 v = *(const float4*)(att + (size_t)(m0 + m) * CC + k0 + kc4);
      As[kc4 + 0][m] = v.x; As[kc4 + 1][m] = v.y;
      As[kc4 + 2][m] = v.z; As[kc4 + 3][m] = v.w;
    }
    {
      const int kc4 = (tid & 3) * 4, n = tid >> 2;
      const float4 v = *(const float4*)(w + (size_t)(n0 + n) * CC + k0 + kc4);
      Bs[kc4 + 0][n] = v.x; Bs[kc4 + 1][n] = v.y;
      Bs[kc4 + 2][n] = v.z; Bs[kc4 + 3][n] = v.w;
    }
    __syncthreads();
#pragma unroll
    for (int kc = 0; kc < 16; ++kc) {
      float a[4], bb[4];
#pragma unroll
      for (int i = 0; i < 4; ++i) a[i] = As[kc][tm + 16 * i];
#pragma unroll
      for (int j = 0; j < 4; ++j) bb[j] = Bs[kc][tn + 16 * j];
#pragma unroll
      for (int i = 0; i < 4; ++i)
#pragma unroll
        for (int j = 0; j < 4; ++j) acc[i][j] += a[i] * bb[j];
    }
    __syncthreads();
  }
#pragma unroll
  for (int j = 0; j < 4; ++j) {
    const int o = n0 + tn + 16 * j;
#pragma unroll
    for (int i = 0; i < 4; ++i) {
      const int s = m0 + tm + 16 * i;
      out[(size_t)o * SD + s] = acc[i][j] + b[o];
    }
  }
}

extern "C" void kernel_launch(void* const* d_in, const int* in_sizes, int n_in,
                              void* d_out, int out_size, void* d_ws, size_t ws_size,
                              hipStream_t stream) {
  const float* x     = (const float*)d_in[0];
  const float* w_qkv = (const float*)d_in[1];
  const float* b_qkv = (const float*)d_in[2];
  const float* w_out = (const float*)d_in[3];
  const float* b_out = (const float*)d_in[4];
  float* out = (float*)d_out;

  float* qkv = (float*)d_ws;                   // [S][768]  28.3 MB
  float* att = qkv + (size_t)SD * NO;          // [S][256]   9.4 MB

  dim3 g1(SD / 64, NO / 64);   // 144 x 12
  qkv_gemm<<<g1, dim3(256), 0, stream>>>(x, w_qkv, b_qkv, qkv);

  nattn<<<dim3(SD * NH / 4), dim3(256), 0, stream>>>(qkv, att);

  dim3 g3(SD / 64, CC / 64);   // 144 x 4
  out_gemm<<<g3, dim3(256), 0, stream>>>(att, w_out, b_out, out);
}

// Round 2
// 147.092 us; speedup vs baseline: 1.6460x; 1.6460x over previous
//
#include <hip/hip_runtime.h>
#include <hip/hip_bf16.h>
#include <math.h>

#define SD 9216   // S = H*W
#define HH 96     // H = W
#define CC 256    // C
#define NO 768    // 3*C
#define NH 8      // heads
#define DH 32     // head dim
#define NW1 (NO * CC)
#define NWT (NW1 + CC * CC)

typedef short bf16x8 __attribute__((ext_vector_type(8)));
typedef float f32x4 __attribute__((ext_vector_type(4)));
typedef unsigned short us8 __attribute__((ext_vector_type(8)));

__device__ __forceinline__ float bf2f(unsigned short u) {
  union { unsigned u; float f; } c; c.u = ((unsigned)u) << 16; return c.f;
}
__device__ __forceinline__ unsigned short f2bf(float f) {
  unsigned u = __float_as_uint(f);
  unsigned r = (u + 0x7FFF + ((u >> 16) & 1)) >> 16;  // RNE
  return (unsigned short)r;
}

// ---- convert both weight matrices f32 -> bf16 (contiguous dst: wqb then wob)
__global__ __launch_bounds__(256) void conv_w(const float* __restrict__ wq,
                                              const float* __restrict__ wo,
                                              unsigned short* __restrict__ dst) {
  const int i = (blockIdx.x * 256 + threadIdx.x) * 4;
  if (i >= NWT) return;
  const float* src = (i < NW1) ? (wq + i) : (wo + (i - NW1));
  const float4 v = *(const float4*)src;
  ushort4 o;
  o.x = f2bf(v.x); o.y = f2bf(v.y); o.z = f2bf(v.z); o.w = f2bf(v.w);
  *(ushort4*)(dst + i) = o;
}

// ---- transpose+convert x [C][S] f32 -> xbt [S][C] bf16 (32x32 LDS tiles)
__global__ __launch_bounds__(256) void transpose_x(const float* __restrict__ x,
                                                   unsigned short* __restrict__ xbt) {
  __shared__ float tile[32][33];
  const int s0 = blockIdx.x * 32;
  const int c0 = blockIdx.y * 32;
  const int t = threadIdx.x;
  {
    const int c = t >> 3, s4 = (t & 7) * 4;
    const float4 v = *(const float4*)(x + (size_t)(c0 + c) * SD + s0 + s4);
    tile[c][s4] = v.x; tile[c][s4 + 1] = v.y; tile[c][s4 + 2] = v.z; tile[c][s4 + 3] = v.w;
  }
  __syncthreads();
  {
    const int s = t >> 3, c4 = (t & 7) * 4;
    ushort4 o;
    o.x = f2bf(tile[c4][s]);     o.y = f2bf(tile[c4 + 1][s]);
    o.z = f2bf(tile[c4 + 2][s]); o.w = f2bf(tile[c4 + 3][s]);
    *(ushort4*)(xbt + (size_t)(s0 + s) * CC + c0 + c4) = o;
  }
}

// ---- bf16 MFMA GEMM, 128x128 tile, BK=32, 4 waves, K = CC = 256 for both uses.
// A: [Mrows][CC] bf16 (rows = D-row dim), Bm: [Nrows][CC] bf16 (rows = D-col dim).
// EPI 0: D[s][o] bf16 row-major stride NO, bias[o]   (qkv projection)
// EPI 1: D[o][s] f32, stride SD, bias[o]=bias[m-dim] (out projection)
template <int EPI>
__global__ __launch_bounds__(256) void gemm_mfma(const unsigned short* __restrict__ A,
                                                 const unsigned short* __restrict__ Bm,
                                                 const float* __restrict__ bias,
                                                 void* __restrict__ out) {
  __shared__ short Asd[128 * 40];  // [row][k] padded 32->40 elems (2-way max)
  __shared__ short Bsd[128 * 40];
  const int t = threadIdx.x;
  const int m0 = blockIdx.x * 128;
  const int n0 = blockIdx.y * 128;
  const int lane = t & 63;
  const int w = t >> 6;
  const int wm = (w >> 1) * 64, wn = (w & 1) * 64;
  f32x4 acc[4][4] = {};
  const int r0 = t >> 2, c16 = (t & 3) * 8;  // staging coords

  for (int k0 = 0; k0 < CC; k0 += 32) {
#pragma unroll
    for (int i = 0; i < 2; ++i) {
      const int r = i * 64 + r0;
      *(int4*)&Asd[r * 40 + c16] = *(const int4*)(A + (size_t)(m0 + r) * CC + k0 + c16);
      *(int4*)&Bsd[r * 40 + c16] = *(const int4*)(Bm + (size_t)(n0 + r) * CC + k0 + c16);
    }
    __syncthreads();
    const int lr = lane & 15, lk = (lane >> 4) * 8;
    bf16x8 af[4], bf[4];
#pragma unroll
    for (int i = 0; i < 4; ++i) af[i] = *(const bf16x8*)&Asd[(wm + i * 16 + lr) * 40 + lk];
#pragma unroll
    for (int j = 0; j < 4; ++j) bf[j] = *(const bf16x8*)&Bsd[(wn + j * 16 + lr) * 40 + lk];
#pragma unroll
    for (int i = 0; i < 4; ++i)
#pragma unroll
      for (int j = 0; j < 4; ++j)
        acc[i][j] = __builtin_amdgcn_mfma_f32_16x16x32_bf16(af[i], bf[j], acc[i][j], 0, 0, 0);
    __syncthreads();
  }

  const int lc = lane & 15, lr4 = (lane >> 4) * 4;
  if (EPI == 0) {
    unsigned short* O = (unsigned short*)out;
#pragma unroll
    for (int i = 0; i < 4; ++i)
#pragma unroll
      for (int j = 0; j < 4; ++j) {
        const int oo = n0 + wn + j * 16 + lc;
        const float bb = bias[oo];
#pragma unroll
        for (int r = 0; r < 4; ++r) {
          const int ss = m0 + wm + i * 16 + lr4 + r;
          O[(size_t)ss * NO + oo] = f2bf(acc[i][j][r] + bb);
        }
      }
  } else {
    float* O = (float*)out;
#pragma unroll
    for (int i = 0; i < 4; ++i)
#pragma unroll
      for (int j = 0; j < 4; ++j) {
#pragma unroll
        for (int r = 0; r < 4; ++r) {
          const int oo = m0 + wm + i * 16 + lr4 + r;
          const int ss = n0 + wn + j * 16 + lc;
          O[(size_t)oo * SD + ss] = acc[i][j][r] + bias[oo];
        }
      }
  }
}

// ---- neighborhood attention: one wave per (s, head), bf16 qkv in, bf16 att out
__global__ __launch_bounds__(256) void nattn(const unsigned short* __restrict__ qkv,
                                             unsigned short* __restrict__ att) {
  const int gw = (blockIdx.x * 256 + threadIdx.x) >> 6;
  const int lane = threadIdx.x & 63;
  const int wv = threadIdx.x >> 6;
  const int h = gw & 7;
  const int s = gw >> 3;

  __shared__ float qsh[4][32];
  __shared__ float psh[4][52];
  __shared__ int nsh[4][52];

  const int i = s / HH, j = s - i * HH;
  const int ri = min(max(i, 3), HH - 4) - 3;  // clamped window start row
  const int cj = min(max(j, 3), HH - 4) - 3;  // clamped window start col

  if (lane < 32) qsh[wv][lane] = bf2f(qkv[(size_t)s * NO + h * DH + lane]);
  __syncthreads();

  const int nr = ri + lane / 7;
  const int nc = cj + lane % 7;
  const int nidx = nr * HH + nc;

  float score = -1e30f;
  if (lane < 49) {
    const us8* kp = (const us8*)(qkv + (size_t)nidx * NO + CC + h * DH);
    const us8 k0 = kp[0], k1 = kp[1], k2 = kp[2], k3 = kp[3];
    float acc = 0.f;
#pragma unroll
    for (int d = 0; d < 8; ++d) {
      acc += bf2f(k0[d]) * qsh[wv][d];
      acc += bf2f(k1[d]) * qsh[wv][8 + d];
      acc += bf2f(k2[d]) * qsh[wv][16 + d];
      acc += bf2f(k3[d]) * qsh[wv][24 + d];
    }
    score = acc * 0.17677669529663687f;  // 32^-0.5
  }

  float mx = score;
#pragma unroll
  for (int off = 32; off; off >>= 1) mx = fmaxf(mx, __shfl_xor(mx, off));
  float p = (lane < 49) ? __expf(score - mx) : 0.f;
  float sum = p;
#pragma unroll
  for (int off = 32; off; off >>= 1) sum += __shfl_xor(sum, off);
  p /= sum;

  if (lane < 50) {
    psh[wv][lane] = (lane < 49) ? p : 0.f;
    nsh[wv][lane] = (lane < 49) ? nidx : s;  // dummy index stays in-bounds
  }
  __syncthreads();

  // PV: lanes 0-31 even neighbors, 32-63 odd; LDS-broadcast p/nidx for ILP
  const int d = lane & 31;
  const int hi = lane >> 5;
  const unsigned short* vbase = qkv + 2 * CC + h * DH + d;
  float o = 0.f;
#pragma unroll
  for (int tt = 0; tt < 25; ++tt) {
    const int jj = 2 * tt + hi;
    o += psh[wv][jj] * bf2f(vbase[(size_t)nsh[wv][jj] * NO]);
  }
  o += __shfl_xor(o, 32);
  if (lane < 32) att[(size_t)s * CC + h * DH + d] = f2bf(o);
}

extern "C" void kernel_launch(void* const* d_in, const int* in_sizes, int n_in,
                              void* d_out, int out_size, void* d_ws, size_t ws_size,
                              hipStream_t stream) {
  const float* x     = (const float*)d_in[0];
  const float* w_qkv = (const float*)d_in[1];
  const float* b_qkv = (const float*)d_in[2];
  const float* w_out = (const float*)d_in[3];
  const float* b_out = (const float*)d_in[4];
  float* out = (float*)d_out;

  unsigned short* ws   = (unsigned short*)d_ws;
  unsigned short* xbt  = ws;                         // [S][C]    bf16
  unsigned short* wqb  = xbt + (size_t)SD * CC;      // [768][256]
  unsigned short* wob  = wqb + (size_t)NO * CC;      // [256][256]
  unsigned short* qkvb = wob + (size_t)CC * CC;      // [S][768]
  unsigned short* attb = qkvb + (size_t)SD * NO;     // [S][256]

  conv_w<<<dim3(NWT / 4 / 256), dim3(256), 0, stream>>>(w_qkv, w_out, wqb);
  transpose_x<<<dim3(SD / 32, CC / 32), dim3(256), 0, stream>>>(x, xbt);

  gemm_mfma<0><<<dim3(SD / 128, NO / 128), dim3(256), 0, stream>>>(xbt, wqb, b_qkv, qkvb);

  nattn<<<dim3(SD * NH / 4), dim3(256), 0, stream>>>(qkvb, attb);

  gemm_mfma<1><<<dim3(CC / 128, SD / 128), dim3(256), 0, stream>>>(wob, attb, b_out, out);
}

// Round 5
// 118.016 us; speedup vs baseline: 2.0515x; 1.2464x over previous
//
#include <hip/hip_runtime.h>
#include <hip/hip_bf16.h>
#include <math.h>

#define SD 9216   // S = H*W
#define HH 96     // H = W
#define CC 256    // C
#define NO 768    // 3*C
#define NH 8      // heads
#define DH 32     // head dim
#define NW1 (NO * CC)
#define NWT (NW1 + CC * CC)
#define PROW 232  // padded LDS row (shorts) for Ps/Vt

typedef short bf16x8 __attribute__((ext_vector_type(8)));
typedef short short8v __attribute__((ext_vector_type(8)));
typedef float f32x4 __attribute__((ext_vector_type(4)));
typedef unsigned short us8 __attribute__((ext_vector_type(8)));

__device__ __forceinline__ float bf2f(unsigned short u) {
  union { unsigned u; float f; } c; c.u = ((unsigned)u) << 16; return c.f;
}
__device__ __forceinline__ unsigned short f2bf(float f) {
  unsigned u = __float_as_uint(f);
  unsigned r = (u + 0x7FFF + ((u >> 16) & 1)) >> 16;  // RNE
  return (unsigned short)r;
}

// ---- prep: transpose x [C][S] f32 -> xbt [S][C] bf16  AND  convert weights
__global__ __launch_bounds__(256) void prep(const float* __restrict__ x,
                                            const float* __restrict__ wq,
                                            const float* __restrict__ wo,
                                            unsigned short* __restrict__ xbt,
                                            unsigned short* __restrict__ wdst) {
  __shared__ float tile[32][33];
  const int b = blockIdx.x;
  const int t = threadIdx.x;
  if (b < 2304) {
    const int s0 = (b % 288) * 32;
    const int c0 = (b / 288) * 32;
    {
      const int c = t >> 3, s4 = (t & 7) * 4;
      const float4 v = *(const float4*)(x + (size_t)(c0 + c) * SD + s0 + s4);
      tile[c][s4] = v.x; tile[c][s4 + 1] = v.y; tile[c][s4 + 2] = v.z; tile[c][s4 + 3] = v.w;
    }
    __syncthreads();
    {
      const int s = t >> 3, c4 = (t & 7) * 4;
      ushort4 o;
      o.x = f2bf(tile[c4][s]);     o.y = f2bf(tile[c4 + 1][s]);
      o.z = f2bf(tile[c4 + 2][s]); o.w = f2bf(tile[c4 + 3][s]);
      *(ushort4*)(xbt + (size_t)(s0 + s) * CC + c0 + c4) = o;
    }
  } else {
    const int i = ((b - 2304) * 256 + t) * 4;
    if (i < NWT) {
      const float* src = (i < NW1) ? (wq + i) : (wo + (i - NW1));
      const float4 v = *(const float4*)src;
      ushort4 o;
      o.x = f2bf(v.x); o.y = f2bf(v.y); o.z = f2bf(v.z); o.w = f2bf(v.w);
      *(ushort4*)(wdst + i) = o;
    }
  }
}

// ---- bf16 MFMA GEMM, 128x128 tile, BK=32, 4 waves, K = 256.
// EPI 0: D[s][o] bf16 stride NO (qkv proj); EPI 1: D[o][s] f32 stride SD (out proj)
template <int EPI>
__global__ __launch_bounds__(256) void gemm_mfma(const unsigned short* __restrict__ A,
                                                 const unsigned short* __restrict__ Bm,
                                                 const float* __restrict__ bias,
                                                 void* __restrict__ out) {
  __shared__ short Asd[128 * 40];
  __shared__ short Bsd[128 * 40];
  const int t = threadIdx.x;
  const int m0 = blockIdx.x * 128;
  const int n0 = blockIdx.y * 128;
  const int lane = t & 63;
  const int w = t >> 6;
  const int wm = (w >> 1) * 64, wn = (w & 1) * 64;
  f32x4 acc[4][4] = {};
  const int r0 = t >> 2, c16 = (t & 3) * 8;

  for (int k0 = 0; k0 < CC; k0 += 32) {
#pragma unroll
    for (int i = 0; i < 2; ++i) {
      const int r = i * 64 + r0;
      *(int4*)&Asd[r * 40 + c16] = *(const int4*)(A + (size_t)(m0 + r) * CC + k0 + c16);
      *(int4*)&Bsd[r * 40 + c16] = *(const int4*)(Bm + (size_t)(n0 + r) * CC + k0 + c16);
    }
    __syncthreads();
    const int lr = lane & 15, lk = (lane >> 4) * 8;
    bf16x8 af[4], bf[4];
#pragma unroll
    for (int i = 0; i < 4; ++i) af[i] = *(const bf16x8*)&Asd[(wm + i * 16 + lr) * 40 + lk];
#pragma unroll
    for (int j = 0; j < 4; ++j) bf[j] = *(const bf16x8*)&Bsd[(wn + j * 16 + lr) * 40 + lk];
#pragma unroll
    for (int i = 0; i < 4; ++i)
#pragma unroll
      for (int j = 0; j < 4; ++j)
        acc[i][j] = __builtin_amdgcn_mfma_f32_16x16x32_bf16(af[i], bf[j], acc[i][j], 0, 0, 0);
    __syncthreads();
  }

  const int lc = lane & 15, lr4 = (lane >> 4) * 4;
  if (EPI == 0) {
    unsigned short* O = (unsigned short*)out;
#pragma unroll
    for (int i = 0; i < 4; ++i)
#pragma unroll
      for (int j = 0; j < 4; ++j) {
        const int oo = n0 + wn + j * 16 + lc;
        const float bb = bias[oo];
#pragma unroll
        for (int r = 0; r < 4; ++r) {
          const int ss = m0 + wm + i * 16 + lr4 + r;
          O[(size_t)ss * NO + oo] = f2bf(acc[i][j][r] + bb);
        }
      }
  } else {
    float* O = (float*)out;
#pragma unroll
    for (int i = 0; i < 4; ++i)
#pragma unroll
      for (int j = 0; j < 4; ++j) {
#pragma unroll
        for (int r = 0; r < 4; ++r) {
          const int oo = m0 + wm + i * 16 + lr4 + r;
          const int ss = n0 + wn + j * 16 + lc;
          O[(size_t)oo * SD + ss] = acc[i][j][r] + bias[oo];
        }
      }
  }
}

// ---- MFMA neighborhood attention: one block per (8x8 query tile, head)
// Union of 7x7 windows over an 8x8 tile fits in 14x14=196 keys (pad to 208/224).
__global__ __launch_bounds__(256) void nattn_mfma(const unsigned short* __restrict__ qkv,
                                                  unsigned short* __restrict__ att) {
  __shared__ short Vt[32][PROW];       // V^T: [d][key]
  __shared__ short Ps[4][16][PROW];    // per-wave P: [q][key]
  const int t = threadIdx.x;
  const int lane = t & 63;
  const int w = t >> 6;
  const int g = lane >> 4;
  const int qcol = lane & 15;
  const int tile = blockIdx.x;
  const int h = blockIdx.y;
  const int ti = tile / 12, tj = tile % 12;
  const int qi0 = ti * 8, qj0 = tj * 8;
  const int ri0 = min(max(qi0, 3), 92) - 3;  // union row start
  const int cj0 = min(max(qj0, 3), 92) - 3;  // union col start

  // --- stage V -> Vt (register 4x8 transpose); keys >=196 zeroed
  if (t < 224) {
    const int kg4 = t >> 2, dg = t & 3, d0 = dg * 8;
    unsigned short vv[4][8];
#pragma unroll
    for (int kk = 0; kk < 4; ++kk) {
      const int ku = kg4 * 4 + kk;
      if (ku < 196) {
        const unsigned ru = (unsigned)ku / 14u, cu = (unsigned)ku % 14u;
        const int ur = min(ri0 + (int)ru, 95), uc = min(cj0 + (int)cu, 95);
        const us8 vrow = *(const us8*)(qkv + (size_t)(ur * HH + uc) * NO + 2 * CC + h * DH + d0);
#pragma unroll
        for (int jj = 0; jj < 8; ++jj) vv[kk][jj] = vrow[jj];
      } else {
#pragma unroll
        for (int jj = 0; jj < 8; ++jj) vv[kk][jj] = 0;
      }
    }
#pragma unroll
    for (int jj = 0; jj < 8; ++jj) {
      ushort4 o; o.x = vv[0][jj]; o.y = vv[1][jj]; o.z = vv[2][jj]; o.w = vv[3][jj];
      *(ushort4*)&Vt[d0 + jj][kg4 * 4] = o;
    }
  }

  // --- QK^T straight from global (A = K rows, B = Q rows; both [row][k] bf16)
  const int ql = w * 16 + qcol;
  const int qi = qi0 + (ql >> 3), qj = qj0 + (ql & 7);
  const int dr = min(max(qi, 3), 92) - 3 - ri0;  // window offset in union
  const int dc = min(max(qj, 3), 92) - 3 - cj0;

  const bf16x8 qf = *(const bf16x8*)(qkv + (size_t)(qi * HH + qj) * NO + h * DH + g * 8);

  f32x4 c[13];
#pragma unroll
  for (int m = 0; m < 13; ++m) {
    const int ku = min(16 * m + qcol, 195);  // A-row = key index (clamped dup, masked later)
    const unsigned ru = (unsigned)ku / 14u, cu = (unsigned)ku % 14u;
    const int ur = min(ri0 + (int)ru, 95), uc = min(cj0 + (int)cu, 95);
    const bf16x8 kf = *(const bf16x8*)(qkv + (size_t)(ur * HH + uc) * NO + CC + h * DH + g * 8);
    c[m] = __builtin_amdgcn_mfma_f32_16x16x32_bf16(kf, qf, (f32x4){0.f, 0.f, 0.f, 0.f}, 0, 0, 0);
  }

  // --- mask + softmax (lane holds keys {16m+4g+r} of query qcol)
  float mx = -1e30f;
#pragma unroll
  for (int m = 0; m < 13; ++m)
#pragma unroll
    for (int r = 0; r < 4; ++r) {
      const int ku = 16 * m + 4 * g + r;
      const unsigned ru = (unsigned)ku / 14u, cu = (unsigned)ku % 14u;
      const bool ok = (ku < 196) && ((unsigned)((int)ru - dr) <= 6u) && ((unsigned)((int)cu - dc) <= 6u);
      const float s = ok ? c[m][r] * 0.17677669529663687f : -1e30f;
      c[m][r] = s;
      mx = fmaxf(mx, s);
    }
  mx = fmaxf(mx, __shfl_xor(mx, 16));
  mx = fmaxf(mx, __shfl_xor(mx, 32));
  float sum = 0.f;
#pragma unroll
  for (int m = 0; m < 13; ++m)
#pragma unroll
    for (int r = 0; r < 4; ++r) { const float p = __expf(c[m][r] - mx); c[m][r] = p; sum += p; }
  sum += __shfl_xor(sum, 16);
  sum += __shfl_xor(sum, 32);
  const float inv = 1.0f / sum;

#pragma unroll
  for (int m = 0; m < 13; ++m) {
    ushort4 pk;
    pk.x = f2bf(c[m][0] * inv); pk.y = f2bf(c[m][1] * inv);
    pk.z = f2bf(c[m][2] * inv); pk.w = f2bf(c[m][3] * inv);
    *(ushort4*)&Ps[w][qcol][16 * m + 4 * g] = pk;
  }
  if (lane < 32) {  // zero P pad keys [208,224)
    const short8v z = {0, 0, 0, 0, 0, 0, 0, 0};
    *(short8v*)&Ps[w][lane >> 1][208 + (lane & 1) * 8] = z;
  }
  __syncthreads();  // Vt ready (cross-wave) + own Ps visible

  // --- PV: O[q][d] = P[q][k] * V[k][d];  A = Ps rows, B = Vt rows (=V^T)
  f32x4 o0 = {0.f, 0.f, 0.f, 0.f}, o1 = {0.f, 0.f, 0.f, 0.f};
#pragma unroll
  for (int tt = 0; tt < 7; ++tt) {
    const bf16x8 pa = *(const bf16x8*)&Ps[w][qcol][tt * 32 + g * 8];
    const bf16x8 v0 = *(const bf16x8*)&Vt[qcol][tt * 32 + g * 8];
    const bf16x8 v1 = *(const bf16x8*)&Vt[16 + qcol][tt * 32 + g * 8];
    o0 = __builtin_amdgcn_mfma_f32_16x16x32_bf16(pa, v0, o0, 0, 0, 0);
    o1 = __builtin_amdgcn_mfma_f32_16x16x32_bf16(pa, v1, o1, 0, 0, 0);
  }

  // --- epilogue: C layout col=lane&15 (=d), row=4g+r (=query in wave)
#pragma unroll
  for (int r = 0; r < 4; ++r) {
    const int qlr = w * 16 + g * 4 + r;
    const int s = (qi0 + (qlr >> 3)) * HH + qj0 + (qlr & 7);
    unsigned short* ap = att + (size_t)s * CC + h * DH;
    ap[qcol] = f2bf(o0[r]);
    ap[16 + qcol] = f2bf(o1[r]);
  }
}

extern "C" void kernel_launch(void* const* d_in, const int* in_sizes, int n_in,
                              void* d_out, int out_size, void* d_ws, size_t ws_size,
                              hipStream_t stream) {
  const float* x     = (const float*)d_in[0];
  const float* w_qkv = (const float*)d_in[1];
  const float* b_qkv = (const float*)d_in[2];
  const float* w_out = (const float*)d_in[3];
  const float* b_out = (const float*)d_in[4];
  float* out = (float*)d_out;

  unsigned short* ws   = (unsigned short*)d_ws;
  unsigned short* xbt  = ws;                         // [S][C]    bf16
  unsigned short* wqb  = xbt + (size_t)SD * CC;      // [768][256]
  unsigned short* wob  = wqb + (size_t)NO * CC;      // [256][256]
  unsigned short* qkvb = wob + (size_t)CC * CC;      // [S][768]
  unsigned short* attb = qkvb + (size_t)SD * NO;     // [S][256]

  prep<<<dim3(2304 + NWT / 4 / 256), dim3(256), 0, stream>>>(x, w_qkv, w_out, xbt, wqb);

  gemm_mfma<0><<<dim3(SD / 128, NO / 128), dim3(256), 0, stream>>>(xbt, wqb, b_qkv, qkvb);

  nattn_mfma<<<dim3(144, NH), dim3(256), 0, stream>>>(qkvb, attb);

  gemm_mfma<1><<<dim3(CC / 128, SD / 128), dim3(256), 0, stream>>>(wob, attb, b_out, out);
}

// Round 6
// 107.971 us; speedup vs baseline: 2.2424x; 1.0930x over previous
//
#include <hip/hip_runtime.h>
#include <hip/hip_bf16.h>
#include <math.h>

#define SD 9216   // S = H*W
#define HH 96     // H = W
#define CC 256    // C
#define NO 768    // 3*C
#define NH 8      // heads
#define DH 32     // head dim
#define NW1 (NO * CC)
#define NWT (NW1 + CC * CC)
#define PROW 232  // padded LDS row (shorts) for Ps/Vt

typedef short bf16x8 __attribute__((ext_vector_type(8)));
typedef short short8v __attribute__((ext_vector_type(8)));
typedef float f32x4 __attribute__((ext_vector_type(4)));
typedef unsigned short us8 __attribute__((ext_vector_type(8)));

__device__ __forceinline__ float bf2f(unsigned short u) {
  union { unsigned u; float f; } c; c.u = ((unsigned)u) << 16; return c.f;
}
__device__ __forceinline__ unsigned short f2bf(float f) {
  unsigned u = __float_as_uint(f);
  unsigned r = (u + 0x7FFF + ((u >> 16) & 1)) >> 16;  // RNE
  return (unsigned short)r;
}
// async global->LDS, 16B per lane; LDS dest is wave-uniform base + lane*16
__device__ __forceinline__ void gll16(const unsigned short* g, short* l) {
  __builtin_amdgcn_global_load_lds(
      (const __attribute__((address_space(1))) void*)g,
      (__attribute__((address_space(3))) void*)l, 16, 0, 0);
}

// ---- prep: transpose x [C][S] f32 -> xbt [S][C] bf16  AND  convert weights
__global__ __launch_bounds__(256) void prep(const float* __restrict__ x,
                                            const float* __restrict__ wq,
                                            const float* __restrict__ wo,
                                            unsigned short* __restrict__ xbt,
                                            unsigned short* __restrict__ wdst) {
  __shared__ float tile[32][33];
  const int b = blockIdx.x;
  const int t = threadIdx.x;
  if (b < 2304) {
    const int s0 = (b % 288) * 32;
    const int c0 = (b / 288) * 32;
    {
      const int c = t >> 3, s4 = (t & 7) * 4;
      const float4 v = *(const float4*)(x + (size_t)(c0 + c) * SD + s0 + s4);
      tile[c][s4] = v.x; tile[c][s4 + 1] = v.y; tile[c][s4 + 2] = v.z; tile[c][s4 + 3] = v.w;
    }
    __syncthreads();
    {
      const int s = t >> 3, c4 = (t & 7) * 4;
      ushort4 o;
      o.x = f2bf(tile[c4][s]);     o.y = f2bf(tile[c4 + 1][s]);
      o.z = f2bf(tile[c4 + 2][s]); o.w = f2bf(tile[c4 + 3][s]);
      *(ushort4*)(xbt + (size_t)(s0 + s) * CC + c0 + c4) = o;
    }
  } else {
    const int i = ((b - 2304) * 256 + t) * 4;
    if (i < NWT) {
      const float* src = (i < NW1) ? (wq + i) : (wo + (i - NW1));
      const float4 v = *(const float4*)src;
      ushort4 o;
      o.x = f2bf(v.x); o.y = f2bf(v.y); o.z = f2bf(v.z); o.w = f2bf(v.w);
      *(ushort4*)(wdst + i) = o;
    }
  }
}

// ---- bf16 MFMA GEMM, BMxBN tile, BK=64, 4 waves, K = CC = 256.
// global_load_lds staging into linear LDS [rows][64] bf16 with XOR chunk swizzle:
// LDS[r][slot] = G[r][slot ^ (r&7)]; fragment read uses slot = chunk ^ (r&7).
// EPI 0: D[s][o] bf16 stride NO (qkv proj); EPI 1: D[o][s] f32 stride SD (out proj)
template <int BM, int BN, int EPI>
__global__ __launch_bounds__(256) void gemm_gll(const unsigned short* __restrict__ A,
                                                const unsigned short* __restrict__ Bm,
                                                const float* __restrict__ bias,
                                                void* __restrict__ out) {
  constexpr int MI = BM / 32, NJ = BN / 32;
  __shared__ short Asd[BM * 64];
  __shared__ short Bsd[BN * 64];
  const int t = threadIdx.x;
  const int lane = t & 63;
  const int w = t >> 6;
  const int m0 = blockIdx.x * BM;
  const int n0 = blockIdx.y * BN;
  const int wm = (w >> 1) * (BM / 2);
  const int wn = (w & 1) * (BN / 2);
  f32x4 acc[MI][NJ] = {};
  const int l8 = lane >> 3;  // row within an 8-row wave-load
  const int sl = lane & 7;   // 16B slot within 128B row

  for (int k0 = 0; k0 < CC; k0 += 64) {
#pragma unroll
    for (int q = 0; q < BM / 32; ++q) {
      const int r = w * (BM / 4) + q * 8 + l8;
      const int cs = sl ^ (r & 7);
      gll16(A + (size_t)(m0 + r) * CC + k0 + cs * 8, Asd + (w * (BM / 4) + q * 8) * 64);
    }
#pragma unroll
    for (int q = 0; q < BN / 32; ++q) {
      const int r = w * (BN / 4) + q * 8 + l8;
      const int cs = sl ^ (r & 7);
      gll16(Bm + (size_t)(n0 + r) * CC + k0 + cs * 8, Bsd + (w * (BN / 4) + q * 8) * 64);
    }
    __syncthreads();  // drains vmcnt
    const int lr = lane & 15, g = lane >> 4;
#pragma unroll
    for (int kk = 0; kk < 2; ++kk) {
      bf16x8 af[MI], bf[NJ];
#pragma unroll
      for (int i = 0; i < MI; ++i) {
        const int row = wm + i * 16 + lr;
        af[i] = *(const bf16x8*)&Asd[row * 64 + ((kk * 4 + g) ^ (lr & 7)) * 8];
      }
#pragma unroll
      for (int j = 0; j < NJ; ++j) {
        const int row = wn + j * 16 + lr;
        bf[j] = *(const bf16x8*)&Bsd[row * 64 + ((kk * 4 + g) ^ (lr & 7)) * 8];
      }
#pragma unroll
      for (int i = 0; i < MI; ++i)
#pragma unroll
        for (int j = 0; j < NJ; ++j)
          acc[i][j] = __builtin_amdgcn_mfma_f32_16x16x32_bf16(af[i], bf[j], acc[i][j], 0, 0, 0);
    }
    __syncthreads();
  }

  const int lc = lane & 15, lr4 = (lane >> 4) * 4;
  if (EPI == 0) {
    unsigned short* O = (unsigned short*)out;
#pragma unroll
    for (int i = 0; i < MI; ++i)
#pragma unroll
      for (int j = 0; j < NJ; ++j) {
        const int oo = n0 + wn + j * 16 + lc;
        const float bb = bias[oo];
#pragma unroll
        for (int r = 0; r < 4; ++r) {
          const int ss = m0 + wm + i * 16 + lr4 + r;
          O[(size_t)ss * NO + oo] = f2bf(acc[i][j][r] + bb);
        }
      }
  } else {
    float* O = (float*)out;
#pragma unroll
    for (int i = 0; i < MI; ++i)
#pragma unroll
      for (int j = 0; j < NJ; ++j) {
#pragma unroll
        for (int r = 0; r < 4; ++r) {
          const int oo = m0 + wm + i * 16 + lr4 + r;
          const int ss = n0 + wn + j * 16 + lc;
          O[(size_t)oo * SD + ss] = acc[i][j][r] + bias[oo];
        }
      }
  }
}

// ---- MFMA neighborhood attention: one block per (8x8 query tile, head)
// Union of 7x7 windows over an 8x8 tile fits in 14x14=196 keys (pad to 208/224).
__global__ __launch_bounds__(256) void nattn_mfma(const unsigned short* __restrict__ qkv,
                                                  unsigned short* __restrict__ att) {
  __shared__ short Vt[32][PROW];       // V^T: [d][key]
  __shared__ short Ps[4][16][PROW];    // per-wave P: [q][key]
  const int t = threadIdx.x;
  const int lane = t & 63;
  const int w = t >> 6;
  const int g = lane >> 4;
  const int qcol = lane & 15;
  const int tile = blockIdx.x;
  const int h = blockIdx.y;
  const int ti = tile / 12, tj = tile % 12;
  const int qi0 = ti * 8, qj0 = tj * 8;
  const int ri0 = min(max(qi0, 3), 92) - 3;  // union row start
  const int cj0 = min(max(qj0, 3), 92) - 3;  // union col start

  // --- stage V -> Vt (register 4x8 transpose); keys >=196 zeroed
  if (t < 224) {
    const int kg4 = t >> 2, dg = t & 3, d0 = dg * 8;
    unsigned short vv[4][8];
#pragma unroll
    for (int kk = 0; kk < 4; ++kk) {
      const int ku = kg4 * 4 + kk;
      if (ku < 196) {
        const unsigned ru = (unsigned)ku / 14u, cu = (unsigned)ku % 14u;
        const int ur = min(ri0 + (int)ru, 95), uc = min(cj0 + (int)cu, 95);
        const us8 vrow = *(const us8*)(qkv + (size_t)(ur * HH + uc) * NO + 2 * CC + h * DH + d0);
#pragma unroll
        for (int jj = 0; jj < 8; ++jj) vv[kk][jj] = vrow[jj];
      } else {
#pragma unroll
        for (int jj = 0; jj < 8; ++jj) vv[kk][jj] = 0;
      }
    }
#pragma unroll
    for (int jj = 0; jj < 8; ++jj) {
      ushort4 o; o.x = vv[0][jj]; o.y = vv[1][jj]; o.z = vv[2][jj]; o.w = vv[3][jj];
      *(ushort4*)&Vt[d0 + jj][kg4 * 4] = o;
    }
  }

  // --- QK^T straight from global (A = K rows, B = Q rows; both [row][k] bf16)
  const int ql = w * 16 + qcol;
  const int qi = qi0 + (ql >> 3), qj = qj0 + (ql & 7);
  const int dr = min(max(qi, 3), 92) - 3 - ri0;  // window offset in union
  const int dc = min(max(qj, 3), 92) - 3 - cj0;

  const bf16x8 qf = *(const bf16x8*)(qkv + (size_t)(qi * HH + qj) * NO + h * DH + g * 8);

  f32x4 c[13];
#pragma unroll
  for (int m = 0; m < 13; ++m) {
    const int ku = min(16 * m + qcol, 195);  // A-row = key index (clamped dup, masked later)
    const unsigned ru = (unsigned)ku / 14u, cu = (unsigned)ku % 14u;
    const int ur = min(ri0 + (int)ru, 95), uc = min(cj0 + (int)cu, 95);
    const bf16x8 kf = *(const bf16x8*)(qkv + (size_t)(ur * HH + uc) * NO + CC + h * DH + g * 8);
    c[m] = __builtin_amdgcn_mfma_f32_16x16x32_bf16(kf, qf, (f32x4){0.f, 0.f, 0.f, 0.f}, 0, 0, 0);
  }

  // --- mask + softmax (lane holds keys {16m+4g+r} of query qcol)
  float mx = -1e30f;
#pragma unroll
  for (int m = 0; m < 13; ++m)
#pragma unroll
    for (int r = 0; r < 4; ++r) {
      const int ku = 16 * m + 4 * g + r;
      const unsigned ru = (unsigned)ku / 14u, cu = (unsigned)ku % 14u;
      const bool ok = (ku < 196) && ((unsigned)((int)ru - dr) <= 6u) && ((unsigned)((int)cu - dc) <= 6u);
      const float s = ok ? c[m][r] * 0.17677669529663687f : -1e30f;
      c[m][r] = s;
      mx = fmaxf(mx, s);
    }
  mx = fmaxf(mx, __shfl_xor(mx, 16));
  mx = fmaxf(mx, __shfl_xor(mx, 32));
  float sum = 0.f;
#pragma unroll
  for (int m = 0; m < 13; ++m)
#pragma unroll
    for (int r = 0; r < 4; ++r) { const float p = __expf(c[m][r] - mx); c[m][r] = p; sum += p; }
  sum += __shfl_xor(sum, 16);
  sum += __shfl_xor(sum, 32);
  const float inv = 1.0f / sum;

#pragma unroll
  for (int m = 0; m < 13; ++m) {
    ushort4 pk;
    pk.x = f2bf(c[m][0] * inv); pk.y = f2bf(c[m][1] * inv);
    pk.z = f2bf(c[m][2] * inv); pk.w = f2bf(c[m][3] * inv);
    *(ushort4*)&Ps[w][qcol][16 * m + 4 * g] = pk;
  }
  if (lane < 32) {  // zero P pad keys [208,224)
    const short8v z = {0, 0, 0, 0, 0, 0, 0, 0};
    *(short8v*)&Ps[w][lane >> 1][208 + (lane & 1) * 8] = z;
  }
  __syncthreads();  // Vt ready (cross-wave) + own Ps visible

  // --- PV: O[q][d] = P[q][k] * V[k][d];  A = Ps rows, B = Vt rows (=V^T)
  f32x4 o0 = {0.f, 0.f, 0.f, 0.f}, o1 = {0.f, 0.f, 0.f, 0.f};
#pragma unroll
  for (int tt = 0; tt < 7; ++tt) {
    const bf16x8 pa = *(const bf16x8*)&Ps[w][qcol][tt * 32 + g * 8];
    const bf16x8 v0 = *(const bf16x8*)&Vt[qcol][tt * 32 + g * 8];
    const bf16x8 v1 = *(const bf16x8*)&Vt[16 + qcol][tt * 32 + g * 8];
    o0 = __builtin_amdgcn_mfma_f32_16x16x32_bf16(pa, v0, o0, 0, 0, 0);
    o1 = __builtin_amdgcn_mfma_f32_16x16x32_bf16(pa, v1, o1, 0, 0, 0);
  }

  // --- epilogue: C layout col=lane&15 (=d), row=4g+r (=query in wave)
#pragma unroll
  for (int r = 0; r < 4; ++r) {
    const int qlr = w * 16 + g * 4 + r;
    const int s = (qi0 + (qlr >> 3)) * HH + qj0 + (qlr & 7);
    unsigned short* ap = att + (size_t)s * CC + h * DH;
    ap[qcol] = f2bf(o0[r]);
    ap[16 + qcol] = f2bf(o1[r]);
  }
}

extern "C" void kernel_launch(void* const* d_in, const int* in_sizes, int n_in,
                              void* d_out, int out_size, void* d_ws, size_t ws_size,
                              hipStream_t stream) {
  const float* x     = (const float*)d_in[0];
  const float* w_qkv = (const float*)d_in[1];
  const float* b_qkv = (const float*)d_in[2];
  const float* w_out = (const float*)d_in[3];
  const float* b_out = (const float*)d_in[4];
  float* out = (float*)d_out;

  unsigned short* ws   = (unsigned short*)d_ws;
  unsigned short* xbt  = ws;                         // [S][C]    bf16
  unsigned short* wqb  = xbt + (size_t)SD * CC;      // [768][256]
  unsigned short* wob  = wqb + (size_t)NO * CC;      // [256][256]
  unsigned short* qkvb = wob + (size_t)CC * CC;      // [S][768]
  unsigned short* attb = qkvb + (size_t)SD * NO;     // [S][256]

  prep<<<dim3(2304 + NWT / 4 / 256), dim3(256), 0, stream>>>(x, w_qkv, w_out, xbt, wqb);

  gemm_gll<128, 128, 0><<<dim3(SD / 128, NO / 128), dim3(256), 0, stream>>>(xbt, wqb, b_qkv, qkvb);

  nattn_mfma<<<dim3(144, NH), dim3(256), 0, stream>>>(qkvb, attb);

  gemm_gll<64, 128, 1><<<dim3(CC / 64, SD / 128), dim3(256), 0, stream>>>(wob, attb, b_out, out);
}

// Round 7
// 105.740 us; speedup vs baseline: 2.2897x; 1.0211x over previous
//
#include <hip/hip_runtime.h>
#include <hip/hip_bf16.h>
#include <math.h>

#define SD 9216   // S = H*W
#define HH 96     // H = W
#define CC 256    // C
#define NO 768    // 3*C
#define NH 8      // heads
#define DH 32     // head dim
#define NW1 (NO * CC)
#define NWT (NW1 + CC * CC)
#define PROW 232  // padded LDS row (shorts) for Ps/Vt

typedef short bf16x8 __attribute__((ext_vector_type(8)));
typedef short short8v __attribute__((ext_vector_type(8)));
typedef float f32x4 __attribute__((ext_vector_type(4)));
typedef unsigned short us8 __attribute__((ext_vector_type(8)));

__device__ __forceinline__ float bf2f(unsigned short u) {
  union { unsigned u; float f; } c; c.u = ((unsigned)u) << 16; return c.f;
}
__device__ __forceinline__ unsigned short f2bf(float f) {
  unsigned u = __float_as_uint(f);
  unsigned r = (u + 0x7FFF + ((u >> 16) & 1)) >> 16;  // RNE
  return (unsigned short)r;
}
// async global->LDS, 16B per lane; LDS dest is wave-uniform base + lane*16
__device__ __forceinline__ void gll16(const unsigned short* g, short* l) {
  __builtin_amdgcn_global_load_lds(
      (const __attribute__((address_space(1))) void*)g,
      (__attribute__((address_space(3))) void*)l, 16, 0, 0);
}

// ---- prep: transpose x [C][S] f32 -> xbt [S][C] bf16  AND  convert weights
__global__ __launch_bounds__(256) void prep(const float* __restrict__ x,
                                            const float* __restrict__ wq,
                                            const float* __restrict__ wo,
                                            unsigned short* __restrict__ xbt,
                                            unsigned short* __restrict__ wdst) {
  __shared__ float tile[32][33];
  const int b = blockIdx.x;
  const int t = threadIdx.x;
  if (b < 2304) {
    const int s0 = (b % 288) * 32;
    const int c0 = (b / 288) * 32;
    {
      const int c = t >> 3, s4 = (t & 7) * 4;
      const float4 v = *(const float4*)(x + (size_t)(c0 + c) * SD + s0 + s4);
      tile[c][s4] = v.x; tile[c][s4 + 1] = v.y; tile[c][s4 + 2] = v.z; tile[c][s4 + 3] = v.w;
    }
    __syncthreads();
    {
      const int s = t >> 3, c4 = (t & 7) * 4;
      ushort4 o;
      o.x = f2bf(tile[c4][s]);     o.y = f2bf(tile[c4 + 1][s]);
      o.z = f2bf(tile[c4 + 2][s]); o.w = f2bf(tile[c4 + 3][s]);
      *(ushort4*)(xbt + (size_t)(s0 + s) * CC + c0 + c4) = o;
    }
  } else {
    const int i = ((b - 2304) * 256 + t) * 4;
    if (i < NWT) {
      const float* src = (i < NW1) ? (wq + i) : (wo + (i - NW1));
      const float4 v = *(const float4*)src;
      ushort4 o;
      o.x = f2bf(v.x); o.y = f2bf(v.y); o.z = f2bf(v.z); o.w = f2bf(v.w);
      *(ushort4*)(wdst + i) = o;
    }
  }
}

// ---- bf16 MFMA GEMM, BMxBN tile, BK=64, 4 waves, K = CC = 256.
// global_load_lds staging, XOR chunk swizzle (both-sides). LDS-bounce epilogue:
// EPI 0: D[s][o] bf16 stride NO (qkv proj); EPI 1: D[o][s] f32 stride SD (out proj)
template <int BM, int BN, int EPI>
__global__ __launch_bounds__(256) void gemm_gll(const unsigned short* __restrict__ A,
                                                const unsigned short* __restrict__ Bm,
                                                const float* __restrict__ bias,
                                                void* __restrict__ out) {
  constexpr int MI = BM / 32, NJ = BN / 32;
  constexpr int STAGE_SH = (BM + BN) * 64;
  constexpr int CT_SH = (EPI == 0) ? BM * (BN + 8) : 2 * BM * (BN + 4);
  constexpr int SMEM_SH = STAGE_SH > CT_SH ? STAGE_SH : CT_SH;
  __shared__ __align__(16) short smem[SMEM_SH];
  short* Asd = smem;
  short* Bsd = smem + BM * 64;
  const int t = threadIdx.x;
  const int lane = t & 63;
  const int w = t >> 6;
  const int m0 = blockIdx.x * BM;
  const int n0 = blockIdx.y * BN;
  const int wm = (w >> 1) * (BM / 2);
  const int wn = (w & 1) * (BN / 2);
  f32x4 acc[MI][NJ] = {};
  const int l8 = lane >> 3;  // row within an 8-row wave-load
  const int sl = lane & 7;   // 16B slot within 128B row

  for (int k0 = 0; k0 < CC; k0 += 64) {
#pragma unroll
    for (int q = 0; q < BM / 32; ++q) {
      const int r = w * (BM / 4) + q * 8 + l8;
      const int cs = sl ^ (r & 7);
      gll16(A + (size_t)(m0 + r) * CC + k0 + cs * 8, Asd + (w * (BM / 4) + q * 8) * 64);
    }
#pragma unroll
    for (int q = 0; q < BN / 32; ++q) {
      const int r = w * (BN / 4) + q * 8 + l8;
      const int cs = sl ^ (r & 7);
      gll16(Bm + (size_t)(n0 + r) * CC + k0 + cs * 8, Bsd + (w * (BN / 4) + q * 8) * 64);
    }
    __syncthreads();  // drains vmcnt
    const int lr = lane & 15, g = lane >> 4;
#pragma unroll
    for (int kk = 0; kk < 2; ++kk) {
      bf16x8 af[MI], bf[NJ];
#pragma unroll
      for (int i = 0; i < MI; ++i) {
        const int row = wm + i * 16 + lr;
        af[i] = *(const bf16x8*)&Asd[row * 64 + ((kk * 4 + g) ^ (lr & 7)) * 8];
      }
#pragma unroll
      for (int j = 0; j < NJ; ++j) {
        const int row = wn + j * 16 + lr;
        bf[j] = *(const bf16x8*)&Bsd[row * 64 + ((kk * 4 + g) ^ (lr & 7)) * 8];
      }
#pragma unroll
      for (int i = 0; i < MI; ++i)
#pragma unroll
        for (int j = 0; j < NJ; ++j)
          acc[i][j] = __builtin_amdgcn_mfma_f32_16x16x32_bf16(af[i], bf[j], acc[i][j], 0, 0, 0);
    }
    __syncthreads();
  }

  const int lc = lane & 15, lr4 = (lane >> 4) * 4;
  if (EPI == 0) {
    // scatter C-frags to LDS bf16 tile, then coalesced 16B row stores
    unsigned short* O = (unsigned short*)out;
    unsigned short* Ct = (unsigned short*)smem;
#pragma unroll
    for (int i = 0; i < MI; ++i)
#pragma unroll
      for (int j = 0; j < NJ; ++j) {
        const float bb = bias[n0 + wn + j * 16 + lc];
#pragma unroll
        for (int r = 0; r < 4; ++r)
          Ct[(wm + i * 16 + lr4 + r) * (BN + 8) + wn + j * 16 + lc] = f2bf(acc[i][j][r] + bb);
      }
    __syncthreads();
#pragma unroll
    for (int rep = 0; rep < BM * BN / 8 / 256; ++rep) {
      const int c = rep * 256 + t;
      const int lrow = c / (BN / 8), lcol8 = (c % (BN / 8)) * 8;
      *(us8*)(O + (size_t)(m0 + lrow) * NO + n0 + lcol8) =
          *(const us8*)&Ct[lrow * (BN + 8) + lcol8];
    }
  } else {
    float* O = (float*)out;
    float* Cf = (float*)smem;
#pragma unroll
    for (int i = 0; i < MI; ++i)
#pragma unroll
      for (int j = 0; j < NJ; ++j) {
#pragma unroll
        for (int r = 0; r < 4; ++r) {
          const int lrow = wm + i * 16 + lr4 + r;
          Cf[lrow * (BN + 4) + wn + j * 16 + lc] = acc[i][j][r] + bias[m0 + lrow];
        }
      }
    __syncthreads();
#pragma unroll
    for (int rep = 0; rep < BM * BN / 4 / 256; ++rep) {
      const int c = rep * 256 + t;
      const int lrow = c / (BN / 4), lcol4 = (c % (BN / 4)) * 4;
      *(float4*)(O + (size_t)(m0 + lrow) * SD + n0 + lcol4) =
          *(const float4*)&Cf[lrow * (BN + 4) + lcol4];
    }
  }
}

// ---- MFMA neighborhood attention: one block per (8x8 query tile, head)
// offs[] table kills per-fragment div/clamp math; V gathers issued to regs
// before QK^T (T14), ds_written to Vt after softmax.
__global__ __launch_bounds__(256) void nattn_mfma(const unsigned short* __restrict__ qkv,
                                                  unsigned short* __restrict__ att) {
  __shared__ int offs[224];            // key element-offset (row*NO) into qkv
  __shared__ short Vt[32][PROW];       // V^T: [d][key]
  __shared__ short Ps[4][16][PROW];    // per-wave P: [q][key]
  const int t = threadIdx.x;
  const int lane = t & 63;
  const int w = t >> 6;
  const int g = lane >> 4;
  const int qcol = lane & 15;
  const int tile = blockIdx.x;
  const int h = blockIdx.y;
  const int ti = tile / 12, tj = tile % 12;
  const int qi0 = ti * 8, qj0 = tj * 8;
  const int ri0 = min(max(qi0, 3), 92) - 3;  // union row start
  const int cj0 = min(max(qj0, 3), 92) - 3;  // union col start

  if (t < 224) {
    const int kr = min(t, 195);
    const int ru = kr / 14, cu = kr - ru * 14;
    offs[t] = (min(ri0 + ru, 95) * HH + min(cj0 + cu, 95)) * NO;
  }

  // Q fragment (independent of offs)
  const int ql = w * 16 + qcol;
  const int qi = qi0 + (ql >> 3), qj = qj0 + (ql & 7);
  const int dr = min(max(qi, 3), 92) - 3 - ri0;  // window offset in union
  const int dc = min(max(qj, 3), 92) - 3 - cj0;
  const bf16x8 qf = *(const bf16x8*)(qkv + (size_t)(qi * HH + qj) * NO + h * DH + g * 8);
  __syncthreads();  // offs ready

  // T14 issue-early: V gathers into registers (keys >=196 read clamped row; P=0 later)
  us8 vreg[4];
  const int kg4 = t >> 2, d0 = (t & 3) * 8;
  if (t < 224) {
#pragma unroll
    for (int kk = 0; kk < 4; ++kk)
      vreg[kk] = *(const us8*)(qkv + (size_t)offs[kg4 * 4 + kk] + 2 * CC + h * DH + d0);
  }

  // QK^T: A = K rows (via offs), B = Q rows
  f32x4 c[13];
#pragma unroll
  for (int m = 0; m < 13; ++m) {
    const bf16x8 kf = *(const bf16x8*)(qkv + (size_t)offs[16 * m + qcol] + CC + h * DH + g * 8);
    c[m] = __builtin_amdgcn_mfma_f32_16x16x32_bf16(kf, qf, (f32x4){0.f, 0.f, 0.f, 0.f}, 0, 0, 0);
  }

  // mask + softmax (lane holds keys {16m+4g+r} of query qcol)
  float mx = -1e30f;
#pragma unroll
  for (int m = 0; m < 13; ++m)
#pragma unroll
    for (int r = 0; r < 4; ++r) {
      const int ku = 16 * m + 4 * g + r;
      const unsigned ru = (unsigned)ku / 14u, cu = (unsigned)ku % 14u;
      const bool ok = (ku < 196) && ((unsigned)((int)ru - dr) <= 6u) && ((unsigned)((int)cu - dc) <= 6u);
      const float s = ok ? c[m][r] * 0.17677669529663687f : -1e30f;
      c[m][r] = s;
      mx = fmaxf(mx, s);
    }
  mx = fmaxf(mx, __shfl_xor(mx, 16));
  mx = fmaxf(mx, __shfl_xor(mx, 32));
  float sum = 0.f;
#pragma unroll
  for (int m = 0; m < 13; ++m)
#pragma unroll
    for (int r = 0; r < 4; ++r) { const float p = __expf(c[m][r] - mx); c[m][r] = p; sum += p; }
  sum += __shfl_xor(sum, 16);
  sum += __shfl_xor(sum, 32);
  const float inv = 1.0f / sum;

#pragma unroll
  for (int m = 0; m < 13; ++m) {
    ushort4 pk;
    pk.x = f2bf(c[m][0] * inv); pk.y = f2bf(c[m][1] * inv);
    pk.z = f2bf(c[m][2] * inv); pk.w = f2bf(c[m][3] * inv);
    *(ushort4*)&Ps[w][qcol][16 * m + 4 * g] = pk;
  }
  if (lane < 32) {  // zero P pad keys [208,224)
    const short8v z = {0, 0, 0, 0, 0, 0, 0, 0};
    *(short8v*)&Ps[w][lane >> 1][208 + (lane & 1) * 8] = z;
  }

  // write-late: V register transpose -> Vt
  if (t < 224) {
#pragma unroll
    for (int jj = 0; jj < 8; ++jj) {
      ushort4 o;
      o.x = vreg[0][jj]; o.y = vreg[1][jj]; o.z = vreg[2][jj]; o.w = vreg[3][jj];
      *(ushort4*)&Vt[d0 + jj][kg4 * 4] = o;
    }
  }
  __syncthreads();  // Vt + Ps visible

  // PV: O[q][d] = P[q][k] * V[k][d];  A = Ps rows, B = Vt rows (=V^T)
  f32x4 o0 = {0.f, 0.f, 0.f, 0.f}, o1 = {0.f, 0.f, 0.f, 0.f};
#pragma unroll
  for (int tt = 0; tt < 7; ++tt) {
    const bf16x8 pa = *(const bf16x8*)&Ps[w][qcol][tt * 32 + g * 8];
    const bf16x8 v0 = *(const bf16x8*)&Vt[qcol][tt * 32 + g * 8];
    const bf16x8 v1 = *(const bf16x8*)&Vt[16 + qcol][tt * 32 + g * 8];
    o0 = __builtin_amdgcn_mfma_f32_16x16x32_bf16(pa, v0, o0, 0, 0, 0);
    o1 = __builtin_amdgcn_mfma_f32_16x16x32_bf16(pa, v1, o1, 0, 0, 0);
  }

  // epilogue: C layout col=lane&15 (=d), row=4g+r (=query in wave)
#pragma unroll
  for (int r = 0; r < 4; ++r) {
    const int qlr = w * 16 + g * 4 + r;
    const int s = (qi0 + (qlr >> 3)) * HH + qj0 + (qlr & 7);
    unsigned short* ap = att + (size_t)s * CC + h * DH;
    ap[qcol] = f2bf(o0[r]);
    ap[16 + qcol] = f2bf(o1[r]);
  }
}

extern "C" void kernel_launch(void* const* d_in, const int* in_sizes, int n_in,
                              void* d_out, int out_size, void* d_ws, size_t ws_size,
                              hipStream_t stream) {
  const float* x     = (const float*)d_in[0];
  const float* w_qkv = (const float*)d_in[1];
  const float* b_qkv = (const float*)d_in[2];
  const float* w_out = (const float*)d_in[3];
  const float* b_out = (const float*)d_in[4];
  float* out = (float*)d_out;

  unsigned short* ws   = (unsigned short*)d_ws;
  unsigned short* xbt  = ws;                         // [S][C]    bf16
  unsigned short* wqb  = xbt + (size_t)SD * CC;      // [768][256]
  unsigned short* wob  = wqb + (size_t)NO * CC;      // [256][256]
  unsigned short* qkvb = wob + (size_t)CC * CC;      // [S][768]
  unsigned short* attb = qkvb + (size_t)SD * NO;     // [S][256]

  prep<<<dim3(2304 + NWT / 4 / 256), dim3(256), 0, stream>>>(x, w_qkv, w_out, xbt, wqb);

  gemm_gll<128, 128, 0><<<dim3(SD / 128, NO / 128), dim3(256), 0, stream>>>(xbt, wqb, b_qkv, qkvb);

  nattn_mfma<<<dim3(144, NH), dim3(256), 0, stream>>>(qkvb, attb);

  gemm_gll<64, 128, 1><<<dim3(CC / 64, SD / 128), dim3(256), 0, stream>>>(wob, attb, b_out, out);
}

// Round 8
// 101.787 us; speedup vs baseline: 2.3786x; 1.0388x over previous
//
#include <hip/hip_runtime.h>
#include <hip/hip_bf16.h>
#include <math.h>

#define SD 9216   // S = H*W
#define HH 96     // H = W
#define CC 256    // C
#define NO 768    // 3*C
#define NH 8      // heads
#define DH 32     // head dim
#define NW1 (NO * CC)
#define NWT (NW1 + CC * CC)
#define PROW 232  // padded LDS row (shorts) for Vt

typedef short bf16x8 __attribute__((ext_vector_type(8)));
typedef float f32x4 __attribute__((ext_vector_type(4)));
typedef unsigned short us8 __attribute__((ext_vector_type(8)));

__device__ __forceinline__ unsigned short f2bf(float f) {
  unsigned u = __float_as_uint(f);
  unsigned r = (u + 0x7FFF + ((u >> 16) & 1)) >> 16;  // RNE
  return (unsigned short)r;
}
// async global->LDS, 16B per lane; LDS dest is wave-uniform base + lane*16
__device__ __forceinline__ void gll16(const unsigned short* g, short* l) {
  __builtin_amdgcn_global_load_lds(
      (const __attribute__((address_space(1))) void*)g,
      (__attribute__((address_space(3))) void*)l, 16, 0, 0);
}

// ---- prep: transpose x [C][S] f32 -> xbt [S][C] bf16  AND  convert weights
__global__ __launch_bounds__(256) void prep(const float* __restrict__ x,
                                            const float* __restrict__ wq,
                                            const float* __restrict__ wo,
                                            unsigned short* __restrict__ xbt,
                                            unsigned short* __restrict__ wdst) {
  __shared__ float tile[32][33];
  const int b = blockIdx.x;
  const int t = threadIdx.x;
  if (b < 2304) {
    const int s0 = (b % 288) * 32;
    const int c0 = (b / 288) * 32;
    {
      const int c = t >> 3, s4 = (t & 7) * 4;
      const float4 v = *(const float4*)(x + (size_t)(c0 + c) * SD + s0 + s4);
      tile[c][s4] = v.x; tile[c][s4 + 1] = v.y; tile[c][s4 + 2] = v.z; tile[c][s4 + 3] = v.w;
    }
    __syncthreads();
    {
      const int s = t >> 3, c4 = (t & 7) * 4;
      ushort4 o;
      o.x = f2bf(tile[c4][s]);     o.y = f2bf(tile[c4 + 1][s]);
      o.z = f2bf(tile[c4 + 2][s]); o.w = f2bf(tile[c4 + 3][s]);
      *(ushort4*)(xbt + (size_t)(s0 + s) * CC + c0 + c4) = o;
    }
  } else {
    const int i = ((b - 2304) * 256 + t) * 4;
    if (i < NWT) {
      const float* src = (i < NW1) ? (wq + i) : (wo + (i - NW1));
      const float4 v = *(const float4*)src;
      ushort4 o;
      o.x = f2bf(v.x); o.y = f2bf(v.y); o.z = f2bf(v.z); o.w = f2bf(v.w);
      *(ushort4*)(wdst + i) = o;
    }
  }
}

// ---- bf16 MFMA GEMM, BMxBN tile, BK=64, 4 waves, K = CC = 256.
// global_load_lds staging, XOR chunk swizzle (both-sides). LDS-bounce epilogue:
// EPI 0: D[s][o] bf16 stride NO (qkv proj); EPI 1: D[o][s] f32 stride SD (out proj)
template <int BM, int BN, int EPI>
__global__ __launch_bounds__(256) void gemm_gll(const unsigned short* __restrict__ A,
                                                const unsigned short* __restrict__ Bm,
                                                const float* __restrict__ bias,
                                                void* __restrict__ out) {
  constexpr int MI = BM / 32, NJ = BN / 32;
  constexpr int STAGE_SH = (BM + BN) * 64;
  constexpr int CT_SH = (EPI == 0) ? BM * (BN + 8) : 2 * BM * (BN + 4);
  constexpr int SMEM_SH = STAGE_SH > CT_SH ? STAGE_SH : CT_SH;
  __shared__ __align__(16) short smem[SMEM_SH];
  short* Asd = smem;
  short* Bsd = smem + BM * 64;
  const int t = threadIdx.x;
  const int lane = t & 63;
  const int w = t >> 6;
  const int m0 = blockIdx.x * BM;
  const int n0 = blockIdx.y * BN;
  const int wm = (w >> 1) * (BM / 2);
  const int wn = (w & 1) * (BN / 2);
  f32x4 acc[MI][NJ] = {};
  const int l8 = lane >> 3;  // row within an 8-row wave-load
  const int sl = lane & 7;   // 16B slot within 128B row

  for (int k0 = 0; k0 < CC; k0 += 64) {
#pragma unroll
    for (int q = 0; q < BM / 32; ++q) {
      const int r = w * (BM / 4) + q * 8 + l8;
      const int cs = sl ^ (r & 7);
      gll16(A + (size_t)(m0 + r) * CC + k0 + cs * 8, Asd + (w * (BM / 4) + q * 8) * 64);
    }
#pragma unroll
    for (int q = 0; q < BN / 32; ++q) {
      const int r = w * (BN / 4) + q * 8 + l8;
      const int cs = sl ^ (r & 7);
      gll16(Bm + (size_t)(n0 + r) * CC + k0 + cs * 8, Bsd + (w * (BN / 4) + q * 8) * 64);
    }
    __syncthreads();  // drains vmcnt
    const int lr = lane & 15, g = lane >> 4;
#pragma unroll
    for (int kk = 0; kk < 2; ++kk) {
      bf16x8 af[MI], bf[NJ];
#pragma unroll
      for (int i = 0; i < MI; ++i) {
        const int row = wm + i * 16 + lr;
        af[i] = *(const bf16x8*)&Asd[row * 64 + ((kk * 4 + g) ^ (lr & 7)) * 8];
      }
#pragma unroll
      for (int j = 0; j < NJ; ++j) {
        const int row = wn + j * 16 + lr;
        bf[j] = *(const bf16x8*)&Bsd[row * 64 + ((kk * 4 + g) ^ (lr & 7)) * 8];
      }
#pragma unroll
      for (int i = 0; i < MI; ++i)
#pragma unroll
        for (int j = 0; j < NJ; ++j)
          acc[i][j] = __builtin_amdgcn_mfma_f32_16x16x32_bf16(af[i], bf[j], acc[i][j], 0, 0, 0);
    }
    __syncthreads();
  }

  const int lc = lane & 15, lr4 = (lane >> 4) * 4;
  if (EPI == 0) {
    // scatter C-frags to LDS bf16 tile, then coalesced 16B row stores
    unsigned short* O = (unsigned short*)out;
    unsigned short* Ct = (unsigned short*)smem;
#pragma unroll
    for (int i = 0; i < MI; ++i)
#pragma unroll
      for (int j = 0; j < NJ; ++j) {
        const float bb = bias[n0 + wn + j * 16 + lc];
#pragma unroll
        for (int r = 0; r < 4; ++r)
          Ct[(wm + i * 16 + lr4 + r) * (BN + 8) + wn + j * 16 + lc] = f2bf(acc[i][j][r] + bb);
      }
    __syncthreads();
#pragma unroll
    for (int rep = 0; rep < BM * BN / 8 / 256; ++rep) {
      const int c = rep * 256 + t;
      const int lrow = c / (BN / 8), lcol8 = (c % (BN / 8)) * 8;
      *(us8*)(O + (size_t)(m0 + lrow) * NO + n0 + lcol8) =
          *(const us8*)&Ct[lrow * (BN + 8) + lcol8];
    }
  } else {
    float* O = (float*)out;
    float* Cf = (float*)smem;
#pragma unroll
    for (int i = 0; i < MI; ++i)
#pragma unroll
      for (int j = 0; j < NJ; ++j) {
#pragma unroll
        for (int r = 0; r < 4; ++r) {
          const int lrow = wm + i * 16 + lr4 + r;
          Cf[lrow * (BN + 4) + wn + j * 16 + lc] = acc[i][j][r] + bias[m0 + lrow];
        }
      }
    __syncthreads();
#pragma unroll
    for (int rep = 0; rep < BM * BN / 4 / 256; ++rep) {
      const int c = rep * 256 + t;
      const int lrow = c / (BN / 4), lcol4 = (c % (BN / 4)) * 4;
      *(float4*)(O + (size_t)(m0 + lrow) * SD + n0 + lcol4) =
          *(const float4*)&Cf[lrow * (BN + 4) + lcol4];
    }
  }
}

// ---- MFMA neighborhood attention v2: one block per (8x8 query tile, head).
// Union flattened 14 rows x 16 cols = 224 keys: ru = key>>4 (= compile-time m in
// fragments), cu = key&15 -> window mask is two bitmask tests, no division.
// P stays in registers; PV streams 32-key slices through a 5 KB per-wave LDS
// buffer (intra-wave lgkmcnt, no barrier). LDS 45 KB -> 21 KB.
__global__ __launch_bounds__(256) void nattn_mfma(const unsigned short* __restrict__ qkv,
                                                  unsigned short* __restrict__ att) {
  __shared__ int offs[224];            // key element-offset (row*NO) into qkv
  __shared__ short Vt[32][PROW];       // V^T: [d][key], 224 keys (2 masked cols)
  __shared__ unsigned Pst[4][16][20];  // per-wave P-slice staging (u32 = 2 bf16)
  const int t = threadIdx.x;
  const int lane = t & 63;
  const int w = t >> 6;
  const int g = lane >> 4;
  const int qcol = lane & 15;
  const int tile = blockIdx.x;
  const int h = blockIdx.y;
  const int ti = tile / 12, tj = tile % 12;
  const int qi0 = ti * 8, qj0 = tj * 8;
  const int ri0 = min(max(qi0, 3), 92) - 3;  // union row start
  const int cj0 = min(max(qj0, 3), 92) - 3;  // union col start

  if (t < 224) {
    const int ru = t >> 4, cu = min(t & 15, 13);  // cu 14,15 dup'd (always masked)
    offs[t] = (min(ri0 + ru, 95) * HH + min(cj0 + cu, 95)) * NO;
  }

  // per-query window bitmasks (rows/cols of the 14x16 union)
  const int ql = w * 16 + qcol;
  const int qi = qi0 + (ql >> 3), qj = qj0 + (ql & 7);
  const int dr = min(max(qi, 3), 92) - 3 - ri0;  // in [0,7]
  const int dc = min(max(qj, 3), 92) - 3 - cj0;  // in [0,7]
  const unsigned rowmask = 0x7Fu << dr;
  const unsigned colm4 = (0x7Fu << dc) >> (4 * g);
  const bf16x8 qf = *(const bf16x8*)(qkv + (size_t)(qi * HH + qj) * NO + h * DH + g * 8);
  __syncthreads();  // offs ready

  // T14 issue-early: V gathers into registers
  us8 vreg[4];
  const int kg4 = t >> 2, d0 = (t & 3) * 8;
  if (t < 224) {
#pragma unroll
    for (int kk = 0; kk < 4; ++kk)
      vreg[kk] = *(const us8*)(qkv + (size_t)offs[kg4 * 4 + kk] + 2 * CC + h * DH + d0);
  }

  // QK^T: A = K rows (via offs), B = Q rows; lane holds key 16m+4g+r, query qcol
  f32x4 c[14];
#pragma unroll
  for (int m = 0; m < 14; ++m) {
    const bf16x8 kf = *(const bf16x8*)(qkv + (size_t)offs[16 * m + qcol] + CC + h * DH + g * 8);
    c[m] = __builtin_amdgcn_mfma_f32_16x16x32_bf16(kf, qf, (f32x4){0.f, 0.f, 0.f, 0.f}, 0, 0, 0);
  }

  // mask + softmax: ru = m (compile-time), cu = 4g+r
  float mx = -1e30f;
#pragma unroll
  for (int m = 0; m < 14; ++m)
#pragma unroll
    for (int r = 0; r < 4; ++r) {
      const bool ok = ((rowmask >> m) & 1u) && ((colm4 >> r) & 1u);
      const float s = ok ? c[m][r] * 0.17677669529663687f : -1e30f;
      c[m][r] = s;
      mx = fmaxf(mx, s);
    }
  mx = fmaxf(mx, __shfl_xor(mx, 16));
  mx = fmaxf(mx, __shfl_xor(mx, 32));
  float sum = 0.f;
#pragma unroll
  for (int m = 0; m < 14; ++m)
#pragma unroll
    for (int r = 0; r < 4; ++r) { const float p = __expf(c[m][r] - mx); c[m][r] = p; sum += p; }
  sum += __shfl_xor(sum, 16);
  sum += __shfl_xor(sum, 32);
  const float inv = 1.0f / sum;

  // pack P to bf16 pairs in registers (keys 4g+2h, 4g+2h+1 of tile m)
  unsigned pk[14][2];
#pragma unroll
  for (int m = 0; m < 14; ++m) {
    pk[m][0] = (unsigned)f2bf(c[m][0] * inv) | ((unsigned)f2bf(c[m][1] * inv) << 16);
    pk[m][1] = (unsigned)f2bf(c[m][2] * inv) | ((unsigned)f2bf(c[m][3] * inv) << 16);
  }

  // write-late: V register transpose -> Vt
  if (t < 224) {
#pragma unroll
    for (int jj = 0; jj < 8; ++jj) {
      ushort4 o;
      o.x = vreg[0][jj]; o.y = vreg[1][jj]; o.z = vreg[2][jj]; o.w = vreg[3][jj];
      *(ushort4*)&Vt[d0 + jj][kg4 * 4] = o;
    }
  }
  __syncthreads();  // Vt visible

  // PV: per 32-key slice, stage own-wave P (lgkmcnt-ordered, no barrier), 2 MFMAs
  f32x4 o0 = {0.f, 0.f, 0.f, 0.f}, o1 = {0.f, 0.f, 0.f, 0.f};
#pragma unroll
  for (int tt = 0; tt < 7; ++tt) {
    *(uint2*)&Pst[w][qcol][2 * g] = make_uint2(pk[2 * tt][0], pk[2 * tt][1]);
    *(uint2*)&Pst[w][qcol][8 + 2 * g] = make_uint2(pk[2 * tt + 1][0], pk[2 * tt + 1][1]);
    const bf16x8 pa = *(const bf16x8*)&Pst[w][qcol][4 * g];  // keys 8g..8g+7, query qcol
    const bf16x8 v0 = *(const bf16x8*)&Vt[qcol][tt * 32 + g * 8];
    const bf16x8 v1 = *(const bf16x8*)&Vt[16 + qcol][tt * 32 + g * 8];
    o0 = __builtin_amdgcn_mfma_f32_16x16x32_bf16(pa, v0, o0, 0, 0, 0);
    o1 = __builtin_amdgcn_mfma_f32_16x16x32_bf16(pa, v1, o1, 0, 0, 0);
  }

  // epilogue: C layout col=lane&15, row=4g+r -> query w*16+4g+r, d = col
#pragma unroll
  for (int r = 0; r < 4; ++r) {
    const int qlr = w * 16 + g * 4 + r;
    const int s = (qi0 + (qlr >> 3)) * HH + qj0 + (qlr & 7);
    unsigned short* ap = att + (size_t)s * CC + h * DH;
    ap[qcol] = f2bf(o0[r]);
    ap[16 + qcol] = f2bf(o1[r]);
  }
}

extern "C" void kernel_launch(void* const* d_in, const int* in_sizes, int n_in,
                              void* d_out, int out_size, void* d_ws, size_t ws_size,
                              hipStream_t stream) {
  const float* x     = (const float*)d_in[0];
  const float* w_qkv = (const float*)d_in[1];
  const float* b_qkv = (const float*)d_in[2];
  const float* w_out = (const float*)d_in[3];
  const float* b_out = (const float*)d_in[4];
  float* out = (float*)d_out;

  unsigned short* ws   = (unsigned short*)d_ws;
  unsigned short* xbt  = ws;                         // [S][C]    bf16
  unsigned short* wqb  = xbt + (size_t)SD * CC;      // [768][256]
  unsigned short* wob  = wqb + (size_t)NO * CC;      // [256][256]
  unsigned short* qkvb = wob + (size_t)CC * CC;      // [S][768]
  unsigned short* attb = qkvb + (size_t)SD * NO;     // [S][256]

  prep<<<dim3(2304 + NWT / 4 / 256), dim3(256), 0, stream>>>(x, w_qkv, w_out, xbt, wqb);

  gemm_gll<64, 128, 0><<<dim3(SD / 64, NO / 128), dim3(256), 0, stream>>>(xbt, wqb, b_qkv, qkvb);

  nattn_mfma<<<dim3(144, NH), dim3(256), 0, stream>>>(qkvb, attb);

  gemm_gll<64, 128, 1><<<dim3(CC / 64, SD / 128), dim3(256), 0, stream>>>(wob, attb, b_out, out);
}